// Round 1
// baseline (119.529 us; speedup 1.0000x reference)
//
#include <hip/hip_runtime.h>
#include <hip/hip_bf16.h>
#include <cstddef>

// Problem dims (fixed by reference setup_inputs)
#define BB 16
#define SS 128
#define TT 128
#define EE 512

__device__ __forceinline__ float fast_tanh(float x) {
    // tanh(x) = 1 - 2/(exp2(2x*log2e)+1); exact saturation at +-inf args
    float t = __builtin_amdgcn_exp2f(x * 2.8853900817779268f);
    return 1.0f - 2.0f * __builtin_amdgcn_rcpf(t + 1.0f);
}

// ---------------- GEMM: C[M,N] = A[M,K] @ W[K,N] (+ bias[N]) -------------
#define BM 64
#define BN 64
#define BK 16
__global__ __launch_bounds__(256) void gemm_bias(
    const float* __restrict__ A, const float* __restrict__ W,
    const float* __restrict__ bias, float* __restrict__ C,
    int M, int N, int K)
{
    __shared__ float As[BK][BM];   // As[k][m]
    __shared__ float Bs[BK][BN];   // Bs[k][n]
    const int t = threadIdx.x;
    const int rowBase = blockIdx.y * BM;
    const int colBase = blockIdx.x * BN;
    const int ty = t >> 4;         // 0..15 -> 4 rows each
    const int tx = t & 15;         // 0..15 -> 4 cols each

    float acc[4][4];
    #pragma unroll
    for (int i = 0; i < 4; ++i)
        #pragma unroll
        for (int j = 0; j < 4; ++j) acc[i][j] = 0.0f;

    const int ra = t >> 2, ca = (t & 3) * 4;     // A-tile load coords
    const int rb = t >> 4, cb = (t & 15) * 4;    // B-tile load coords

    for (int k0 = 0; k0 < K; k0 += BK) {
        float4 av = *(const float4*)&A[(size_t)(rowBase + ra) * K + k0 + ca];
        As[ca + 0][ra] = av.x;
        As[ca + 1][ra] = av.y;
        As[ca + 2][ra] = av.z;
        As[ca + 3][ra] = av.w;
        float4 bv = *(const float4*)&W[(size_t)(k0 + rb) * N + colBase + cb];
        *(float4*)&Bs[rb][cb] = bv;
        __syncthreads();
        #pragma unroll
        for (int k = 0; k < BK; ++k) {
            float4 a4 = *(const float4*)&As[k][ty * 4];
            float4 b4 = *(const float4*)&Bs[k][tx * 4];
            float aa[4] = {a4.x, a4.y, a4.z, a4.w};
            float bb[4] = {b4.x, b4.y, b4.z, b4.w};
            #pragma unroll
            for (int i = 0; i < 4; ++i)
                #pragma unroll
                for (int j = 0; j < 4; ++j)
                    acc[i][j] = fmaf(aa[i], bb[j], acc[i][j]);
        }
        __syncthreads();
    }

    float4 biasv = make_float4(0.f, 0.f, 0.f, 0.f);
    if (bias) biasv = *(const float4*)&bias[colBase + tx * 4];
    float bv4[4] = {biasv.x, biasv.y, biasv.z, biasv.w};
    #pragma unroll
    for (int i = 0; i < 4; ++i) {
        int row = rowBase + ty * 4 + i;
        #pragma unroll
        for (int j = 0; j < 4; ++j)
            C[(size_t)row * N + colBase + tx * 4 + j] = acc[i][j] + bv4[j];
    }
}

// ------------- fused: tanh-score dot, softmax over S, context ------------
// One block per (b,t). 256 threads = 4 waves.
__global__ __launch_bounds__(256) void attn_fused(
    const float* __restrict__ W1hs,   // [B*S, E]
    const float* __restrict__ W2htb,  // [B*T, E]  (bias already added)
    const float* __restrict__ V,      // [E]
    const float* __restrict__ enc,    // [B*S, E]
    float* __restrict__ ctx,          // [B*T, E]
    float* __restrict__ attn)         // [B*T, S]
{
    const int bt = blockIdx.x;
    const int b  = bt / TT;
    const int tid  = threadIdx.x;
    const int lane = tid & 63;
    const int w    = tid >> 6;

    __shared__ float sm[SS];   // logits, then softmax weights

    // per-lane e-slice: 8 consecutive floats at e = lane*8
    const float4* c2p = (const float4*)(W2htb + (size_t)bt * EE);
    const float4  c0 = c2p[lane * 2], c1 = c2p[lane * 2 + 1];
    const float4* vp = (const float4*)V;
    const float4  v0 = vp[lane * 2], v1 = vp[lane * 2 + 1];

    for (int s = w; s < SS; s += 4) {
        const float4* ap = (const float4*)(W1hs + ((size_t)b * SS + s) * EE);
        float4 x0 = ap[lane * 2], x1 = ap[lane * 2 + 1];
        float acc;
        acc  = v0.x * fast_tanh(x0.x + c0.x);
        acc += v0.y * fast_tanh(x0.y + c0.y);
        acc += v0.z * fast_tanh(x0.z + c0.z);
        acc += v0.w * fast_tanh(x0.w + c0.w);
        acc += v1.x * fast_tanh(x1.x + c1.x);
        acc += v1.y * fast_tanh(x1.y + c1.y);
        acc += v1.z * fast_tanh(x1.z + c1.z);
        acc += v1.w * fast_tanh(x1.w + c1.w);
        #pragma unroll
        for (int off = 32; off >= 1; off >>= 1)
            acc += __shfl_down(acc, off);
        if (lane == 0) sm[s] = acc;
    }
    __syncthreads();

    if (w == 0) {
        float l0 = sm[lane], l1 = sm[lane + 64];
        float m = fmaxf(l0, l1);
        #pragma unroll
        for (int off = 32; off >= 1; off >>= 1)
            m = fmaxf(m, __shfl_xor(m, off));
        const float L2E = 1.4426950408889634f;
        float e0 = __builtin_amdgcn_exp2f((l0 - m) * L2E);
        float e1 = __builtin_amdgcn_exp2f((l1 - m) * L2E);
        float sum = e0 + e1;
        #pragma unroll
        for (int off = 32; off >= 1; off >>= 1)
            sum += __shfl_xor(sum, off);
        float inv = 1.0f / sum;
        float w0v = e0 * inv, w1v = e1 * inv;
        sm[lane]      = w0v;
        sm[lane + 64] = w1v;
        attn[(size_t)bt * SS + lane]      = w0v;
        attn[(size_t)bt * SS + lane + 64] = w1v;
    }
    __syncthreads();

    // context[e] = sum_s w[s] * enc[b,s,e]; thread covers e = tid, tid+256
    float a0 = 0.f, a1 = 0.f;
    const float* encb = enc + (size_t)b * SS * EE;
    for (int s = 0; s < SS; ++s) {
        float wv = sm[s];
        a0 = fmaf(wv, encb[(size_t)s * EE + tid],       a0);
        a1 = fmaf(wv, encb[(size_t)s * EE + tid + 256], a1);
    }
    ctx[(size_t)bt * EE + tid]       = a0;
    ctx[(size_t)bt * EE + tid + 256] = a1;
}

extern "C" void kernel_launch(void* const* d_in, const int* in_sizes, int n_in,
                              void* d_out, int out_size, void* d_ws, size_t ws_size,
                              hipStream_t stream) {
    const float* enc = (const float*)d_in[0];   // [B,S,E]
    const float* dec = (const float*)d_in[1];   // [B,T,D]
    const float* W1  = (const float*)d_in[2];   // [E,E]
    const float* W2  = (const float*)d_in[3];   // [D,E]
    const float* bv  = (const float*)d_in[4];   // [E]
    const float* V   = (const float*)d_in[5];   // [E]

    float* ctx  = (float*)d_out;                      // [B,T,E]
    float* attn = (float*)d_out + (size_t)BB * TT * EE; // [B,T,S]

    float* ws0 = (float*)d_ws;                        // W1hs  [B*S, E]
    float* ws1 = ws0 + (size_t)BB * SS * EE;          // W2htb [B*T, E]

    const int M = BB * SS;  // 2048
    dim3 gblock(256);
    dim3 ggrid(EE / BN, M / BM);   // (8, 32)

    // W1hs = enc @ W1
    gemm_bias<<<ggrid, gblock, 0, stream>>>(enc, W1, nullptr, ws0, M, EE, EE);
    // W2htb = dec @ W2 + b
    gemm_bias<<<ggrid, gblock, 0, stream>>>(dec, W2, bv, ws1, M, EE, EE);
    // fused scores/softmax/context
    attn_fused<<<dim3(BB * TT), dim3(256), 0, stream>>>(ws0, ws1, V, enc, ctx, attn);
}